// Round 1
// baseline (114.528 us; speedup 1.0000x reference)
//
#include <hip/hip_runtime.h>
#include <hip/hip_bf16.h>

#define D_N 512
#define M_N 1024
#define F_N 64

// ---------------------------------------------------------------------------
// Kernel 1: xw[n][k] = comb[n] @ gat_w.T ; u[n] = xw[n] . gat_att[:64]
//   comb[n<D] = c_emb[c_it[n]], comb[n>=D] = m_emb[m_it[n-D]]
// grid = (D+M)/4 blocks of 256 threads (one wave per row)
// ---------------------------------------------------------------------------
__global__ __launch_bounds__(256) void k_xw(
    const int* __restrict__ c_it, const int* __restrict__ m_it,
    const float* __restrict__ c_emb, const float* __restrict__ m_emb,
    const float* __restrict__ gat_w, const float* __restrict__ gat_att,
    float* __restrict__ xw, float* __restrict__ u)
{
    __shared__ float sWt[64 * 65];   // transposed + padded: sWt[j*65+k] = W[k][j]
    __shared__ float sX[4][64];
    const int tid = threadIdx.x;
    for (int idx = tid; idx < 4096; idx += 256) {
        int k = idx >> 6, j = idx & 63;
        sWt[j * 65 + k] = gat_w[idx];
    }
    const int w = tid >> 6, lane = tid & 63;
    const int n = blockIdx.x * 4 + w;
    const float* xr = (n < D_N) ? (c_emb + (size_t)c_it[n] * F_N)
                                : (m_emb + (size_t)m_it[n - D_N] * F_N);
    sX[w][lane] = xr[lane];
    __syncthreads();
    float acc = 0.f;
#pragma unroll
    for (int j = 0; j < 64; ++j)
        acc += sX[w][j] * sWt[j * 65 + lane];
    xw[n * F_N + lane] = acc;
    // u[n] = sum_k xw[n][k] * att[k]
    float p = acc * gat_att[lane];
#pragma unroll
    for (int off = 32; off > 0; off >>= 1)
        p += __shfl_xor(p, off, 64);
    if (lane == 0) u[n] = p;
}

// ---------------------------------------------------------------------------
// Kernel 2: per hyperedge e (one block of 256 threads):
//   v_e = hattr[e] . (att2 @ W)      (att2 = gat_att[64:])
//   softmax over {lrelu(u[e]+v_e)} U {lrelu(u[D+m]+v_e)}_m
//   efeat[k] = (ex_self*xw[e][k] + sum_m ex_m*xw[D+m][k]) / (denom*(M+1))
//   t1[e][k] = a_self * efeat[k];  t2[e][k] = (1-a_self) * efeat[k]
// ---------------------------------------------------------------------------
__global__ __launch_bounds__(256) void k_edge(
    const float* __restrict__ hattr, const float* __restrict__ gat_w,
    const float* __restrict__ gat_att,
    const float* __restrict__ xw, const float* __restrict__ u,
    float* __restrict__ t1, float* __restrict__ t2)
{
    __shared__ float ex[M_N];
    __shared__ float red[4][64];
    __shared__ float rmax[4], rsum[4], sv[1];
    const int e = blockIdx.x;
    const int tid = threadIdx.x;
    const int w = tid >> 6, lane = tid & 63;

    // v_e (wave 0): w2[j] = sum_k att2[k]*W[k][j]; v_e = sum_j hattr[e][j]*w2[j]
    if (w == 0) {
        float w2 = 0.f;
#pragma unroll
        for (int k = 0; k < 64; ++k)
            w2 += gat_att[64 + k] * gat_w[k * 64 + lane];
        float p = hattr[e * F_N + lane] * w2;
#pragma unroll
        for (int off = 32; off > 0; off >>= 1)
            p += __shfl_xor(p, off, 64);
        if (lane == 0) sv[0] = p;
    }
    __syncthreads();
    const float v_e = sv[0];

    // phase 1: leaky-relu'd logits, block max
    float au[4];
    float amax;
    {
        float a_self = u[e] + v_e;
        a_self = a_self > 0.f ? a_self : 0.2f * a_self;
        amax = a_self;   // fold self into every lane's running max
    }
#pragma unroll
    for (int i = 0; i < 4; ++i) {
        int m = tid + i * 256;
        float a = u[D_N + m] + v_e;
        a = a > 0.f ? a : 0.2f * a;
        au[i] = a;
        amax = fmaxf(amax, a);
    }
#pragma unroll
    for (int off = 32; off > 0; off >>= 1)
        amax = fmaxf(amax, __shfl_xor(amax, off, 64));
    if (lane == 0) rmax[w] = amax;
    __syncthreads();
    const float bmax = fmaxf(fmaxf(rmax[0], rmax[1]), fmaxf(rmax[2], rmax[3]));

    // phase 2: exponentials + block sum
    float psum = 0.f;
#pragma unroll
    for (int i = 0; i < 4; ++i) {
        int m = tid + i * 256;
        float exv = expf(au[i] - bmax);
        ex[m] = exv;
        psum += exv;
    }
#pragma unroll
    for (int off = 32; off > 0; off >>= 1)
        psum += __shfl_xor(psum, off, 64);
    if (lane == 0) rsum[w] = psum;
    __syncthreads();   // also makes ex[] visible to all waves
    float a_self = u[e] + v_e;
    a_self = a_self > 0.f ? a_self : 0.2f * a_self;
    const float ex_self = expf(a_self - bmax);
    const float denom = ex_self + rsum[0] + rsum[1] + rsum[2] + rsum[3];

    // phase 3: weighted sum over meds; wave w handles med chunk [w*256, w*256+256)
    float acc = 0.f;
    const float* xm = xw + (size_t)(D_N + w * 256) * F_N + lane;
    for (int m = 0; m < 256; ++m)
        acc += ex[w * 256 + m] * xm[(size_t)m * F_N];
    red[w][lane] = acc;
    __syncthreads();
    if (w == 0) {
        float tot = red[0][lane] + red[1][lane] + red[2][lane] + red[3][lane];
        float ef = (ex_self * xw[e * F_N + lane] + tot) / (denom * (float)(M_N + 1));
        float as = ex_self / denom;
        t1[e * F_N + lane] = as * ef;
        t2[e * F_N + lane] = (1.f - as) * ef;
    }
}

// ---------------------------------------------------------------------------
// Kernel 3: single-block finalize.
//  S1[k]=sum_e t1; S2[k]=(1/D) sum_e t2; P0=sum pe0[c_it]; P1=sum pe1[m_it];
//  MC=mean c_emb[c_it]; MM=mean m_emb[m_it];
//  dia = MC@conv_w.T+conv_b; med = MM@conv_w.T+conv_b;
//  repD = [S1 + D*gat_b | D*dia]; repM = [S2 + M*gat_b | M*med];
//  out[k]     = P0[k] + repD @ lin_w[k,:]
//  out[64+k]  = P1[k] + repM @ lin_w[k,:]
// ---------------------------------------------------------------------------
__global__ __launch_bounds__(256) void k_final(
    const int* __restrict__ c_it, const int* __restrict__ m_it,
    const float* __restrict__ pe0, const float* __restrict__ pe1,
    const float* __restrict__ c_emb, const float* __restrict__ m_emb,
    const float* __restrict__ conv_w, const float* __restrict__ conv_b,
    const float* __restrict__ gat_b, const float* __restrict__ lin_w,
    const float* __restrict__ t1, const float* __restrict__ t2,
    float* __restrict__ out)
{
    __shared__ float red[4][64];
    __shared__ float red2[4][64];
    __shared__ float S1[64], S2[64], P0[64], P1[64], MC[64], MM[64];
    __shared__ float repD[128], repM[128];
    const int tid = threadIdx.x;
    const int c = tid >> 6, k = tid & 63;

    // S1 / S2 over 512 edges
    {
        float a = 0.f, b = 0.f;
        for (int e = c; e < D_N; e += 4) {
            a += t1[e * F_N + k];
            b += t2[e * F_N + k];
        }
        red[c][k] = a; red2[c][k] = b;
    }
    __syncthreads();
    if (c == 0) {
        S1[k] = red[0][k] + red[1][k] + red[2][k] + red[3][k];
        S2[k] = (red2[0][k] + red2[1][k] + red2[2][k] + red2[3][k]) * (1.f / (float)D_N);
    }
    __syncthreads();

    // P0 / MC over D gathered rows
    {
        float a = 0.f, b = 0.f;
        for (int i = c; i < D_N; i += 4) {
            int r = c_it[i];
            a += pe0[(size_t)r * F_N + k];
            b += c_emb[(size_t)r * F_N + k];
        }
        red[c][k] = a; red2[c][k] = b;
    }
    __syncthreads();
    if (c == 0) {
        P0[k] = red[0][k] + red[1][k] + red[2][k] + red[3][k];
        MC[k] = (red2[0][k] + red2[1][k] + red2[2][k] + red2[3][k]) * (1.f / (float)D_N);
    }
    __syncthreads();

    // P1 / MM over M gathered rows
    {
        float a = 0.f, b = 0.f;
        for (int i = c; i < M_N; i += 4) {
            int r = m_it[i];
            a += pe1[(size_t)r * F_N + k];
            b += m_emb[(size_t)r * F_N + k];
        }
        red[c][k] = a; red2[c][k] = b;
    }
    __syncthreads();
    if (c == 0) {
        P1[k] = red[0][k] + red[1][k] + red[2][k] + red[3][k];
        MM[k] = (red2[0][k] + red2[1][k] + red2[2][k] + red2[3][k]) * (1.f / (float)M_N);
    }
    __syncthreads();

    if (tid < 64) {
        float dia = conv_b[k], med = conv_b[k];
        for (int j = 0; j < 64; ++j) {
            dia += MC[j] * conv_w[k * 64 + j];
            med += MM[j] * conv_w[k * 64 + j];
        }
        repD[k]      = S1[k] + (float)D_N * gat_b[k];
        repD[64 + k] = (float)D_N * dia;
        repM[k]      = S2[k] + (float)M_N * gat_b[k];
        repM[64 + k] = (float)M_N * med;
    }
    __syncthreads();
    if (tid < 64) {
        float o1 = P0[k], o2 = P1[k];
        for (int j = 0; j < 128; ++j) {
            o1 += repD[j] * lin_w[k * 128 + j];
            o2 += repM[j] * lin_w[k * 128 + j];
        }
        out[k] = o1;
        out[64 + k] = o2;
    }
}

extern "C" void kernel_launch(void* const* d_in, const int* in_sizes, int n_in,
                              void* d_out, int out_size, void* d_ws, size_t ws_size,
                              hipStream_t stream) {
    const int*   c_it    = (const int*)d_in[0];
    const int*   m_it    = (const int*)d_in[1];
    const float* c_emb   = (const float*)d_in[2];
    const float* m_emb   = (const float*)d_in[3];
    const float* pe0     = (const float*)d_in[4];
    const float* pe1     = (const float*)d_in[5];
    const float* conv_w  = (const float*)d_in[6];
    const float* conv_b  = (const float*)d_in[7];
    const float* gat_w   = (const float*)d_in[8];
    const float* gat_b   = (const float*)d_in[9];
    const float* gat_att = (const float*)d_in[10];
    const float* hattr   = (const float*)d_in[11];
    const float* lin_w   = (const float*)d_in[12];
    float* out = (float*)d_out;

    float* ws = (float*)d_ws;
    float* xw = ws;                                  // (D+M)*64 = 98304
    float* u  = ws + (D_N + M_N) * F_N;              // 1536
    float* t1 = u + (D_N + M_N);                     // D*64 = 32768
    float* t2 = t1 + D_N * F_N;                      // D*64 = 32768

    k_xw<<<(D_N + M_N) / 4, 256, 0, stream>>>(c_it, m_it, c_emb, m_emb,
                                              gat_w, gat_att, xw, u);
    k_edge<<<D_N, 256, 0, stream>>>(hattr, gat_w, gat_att, xw, u, t1, t2);
    k_final<<<1, 256, 0, stream>>>(c_it, m_it, pe0, pe1, c_emb, m_emb,
                                   conv_w, conv_b, gat_b, lin_w, t1, t2, out);
}

// Round 2
// 29.611 us; speedup vs baseline: 3.8677x; 3.8677x over previous
//
#include <hip/hip_runtime.h>
#include <hip/hip_bf16.h>

#define D_N 512
#define M_N 1024
#define F_N 64

// ---------------------------------------------------------------------------
// Kernel 1: xw[n][k] = comb[n] @ gat_w.T ; u[n] = xw[n] . gat_att[:64]
// ---------------------------------------------------------------------------
__global__ __launch_bounds__(256) void k_xw(
    const int* __restrict__ c_it, const int* __restrict__ m_it,
    const float* __restrict__ c_emb, const float* __restrict__ m_emb,
    const float* __restrict__ gat_w, const float* __restrict__ gat_att,
    float* __restrict__ xw, float* __restrict__ u)
{
    __shared__ float sWt[64 * 65];   // transposed + padded: sWt[j*65+k] = W[k][j]
    __shared__ float sX[4][64];
    const int tid = threadIdx.x;
    for (int idx = tid; idx < 4096; idx += 256) {
        int k = idx >> 6, j = idx & 63;
        sWt[j * 65 + k] = gat_w[idx];
    }
    const int w = tid >> 6, lane = tid & 63;
    const int n = blockIdx.x * 4 + w;
    const float* xr = (n < D_N) ? (c_emb + (size_t)c_it[n] * F_N)
                                : (m_emb + (size_t)m_it[n - D_N] * F_N);
    sX[w][lane] = xr[lane];
    __syncthreads();
    float acc = 0.f;
#pragma unroll
    for (int j = 0; j < 64; ++j)
        acc += sX[w][j] * sWt[j * 65 + lane];
    xw[n * F_N + lane] = acc;
    float p = acc * gat_att[lane];
#pragma unroll
    for (int off = 32; off > 0; off >>= 1)
        p += __shfl_xor(p, off, 64);
    if (lane == 0) u[n] = p;
}

// ---------------------------------------------------------------------------
// Kernel 2: per hyperedge e: softmax over {self} U meds, weighted sums.
// ---------------------------------------------------------------------------
__global__ __launch_bounds__(256) void k_edge(
    const float* __restrict__ hattr, const float* __restrict__ gat_w,
    const float* __restrict__ gat_att,
    const float* __restrict__ xw, const float* __restrict__ u,
    float* __restrict__ t1, float* __restrict__ t2)
{
    __shared__ float ex[M_N];
    __shared__ float red[4][64];
    __shared__ float rmax[4], rsum[4], sv[1];
    const int e = blockIdx.x;
    const int tid = threadIdx.x;
    const int w = tid >> 6, lane = tid & 63;

    if (w == 0) {
        float w2 = 0.f;
#pragma unroll
        for (int k = 0; k < 64; ++k)
            w2 += gat_att[64 + k] * gat_w[k * 64 + lane];
        float p = hattr[e * F_N + lane] * w2;
#pragma unroll
        for (int off = 32; off > 0; off >>= 1)
            p += __shfl_xor(p, off, 64);
        if (lane == 0) sv[0] = p;
    }
    __syncthreads();
    const float v_e = sv[0];

    float au[4];
    float amax;
    {
        float a_self = u[e] + v_e;
        a_self = a_self > 0.f ? a_self : 0.2f * a_self;
        amax = a_self;
    }
#pragma unroll
    for (int i = 0; i < 4; ++i) {
        int m = tid + i * 256;
        float a = u[D_N + m] + v_e;
        a = a > 0.f ? a : 0.2f * a;
        au[i] = a;
        amax = fmaxf(amax, a);
    }
#pragma unroll
    for (int off = 32; off > 0; off >>= 1)
        amax = fmaxf(amax, __shfl_xor(amax, off, 64));
    if (lane == 0) rmax[w] = amax;
    __syncthreads();
    const float bmax = fmaxf(fmaxf(rmax[0], rmax[1]), fmaxf(rmax[2], rmax[3]));

    float psum = 0.f;
#pragma unroll
    for (int i = 0; i < 4; ++i) {
        int m = tid + i * 256;
        float exv = expf(au[i] - bmax);
        ex[m] = exv;
        psum += exv;
    }
#pragma unroll
    for (int off = 32; off > 0; off >>= 1)
        psum += __shfl_xor(psum, off, 64);
    if (lane == 0) rsum[w] = psum;
    __syncthreads();
    float a_self = u[e] + v_e;
    a_self = a_self > 0.f ? a_self : 0.2f * a_self;
    const float ex_self = expf(a_self - bmax);
    const float denom = ex_self + rsum[0] + rsum[1] + rsum[2] + rsum[3];

    float acc = 0.f;
    const float* xm = xw + (size_t)(D_N + w * 256) * F_N + lane;
    for (int m = 0; m < 256; ++m)
        acc += ex[w * 256 + m] * xm[(size_t)m * F_N];
    red[w][lane] = acc;
    __syncthreads();
    if (w == 0) {
        float tot = red[0][lane] + red[1][lane] + red[2][lane] + red[3][lane];
        float ef = (ex_self * xw[e * F_N + lane] + tot) / (denom * (float)(M_N + 1));
        float as = ex_self / denom;
        t1[e * F_N + lane] = as * ef;
        t2[e * F_N + lane] = (1.f - as) * ef;
    }
}

// ---------------------------------------------------------------------------
// Kernel G: parallel partial gathers.
//  blocks 0..15 : rows [b*32, b*32+32) of c_it -> partial P0 (pe0) & MC (c_emb)
//  blocks 16..47: rows [(b-16)*32, ..+32) of m_it -> partial P1 (pe1) & MM (m_emb)
//  pp layout: P0 [0,16), MC [16,32), P1 [32,64), MM [64,96)  (each x64 floats)
// ---------------------------------------------------------------------------
__global__ __launch_bounds__(256) void k_gather(
    const int* __restrict__ c_it, const int* __restrict__ m_it,
    const float* __restrict__ pe0, const float* __restrict__ pe1,
    const float* __restrict__ c_emb, const float* __restrict__ m_emb,
    float* __restrict__ pp)
{
    __shared__ float redA[4][64], redB[4][64];
    const int b = blockIdx.x, tid = threadIdx.x;
    const int w = tid >> 6, lane = tid & 63;
    const int* idx; const float* ta; const float* tb;
    int base, outA, outB;
    if (b < 16) { idx = c_it; ta = pe0; tb = c_emb; base = b * 32; outA = b; outB = 16 + b; }
    else { int b2 = b - 16; idx = m_it; ta = pe1; tb = m_emb; base = b2 * 32; outA = 32 + b2; outB = 64 + b2; }
    const int r0 = base + w * 8;
    float a = 0.f, bb = 0.f;
#pragma unroll
    for (int j = 0; j < 8; ++j) {
        int r = idx[r0 + j];
        a  += ta[(size_t)r * F_N + lane];
        bb += tb[(size_t)r * F_N + lane];
    }
    redA[w][lane] = a; redB[w][lane] = bb;
    __syncthreads();
    if (w == 0) {
        pp[outA * 64 + lane] = redA[0][lane] + redA[1][lane] + redA[2][lane] + redA[3][lane];
        pp[outB * 64 + lane] = redB[0][lane] + redB[1][lane] + redB[2][lane] + redB[3][lane];
    }
}

// ---------------------------------------------------------------------------
// Kernel R: reduce t1/t2 over edges in 16 blocks of 32 edges.
//  pt layout: S1 partials [0,16), S2 partials [16,32)
// ---------------------------------------------------------------------------
__global__ __launch_bounds__(256) void k_redt(
    const float* __restrict__ t1, const float* __restrict__ t2,
    float* __restrict__ pt)
{
    __shared__ float redA[4][64], redB[4][64];
    const int b = blockIdx.x, tid = threadIdx.x;
    const int w = tid >> 6, lane = tid & 63;
    const int e0 = b * 32 + w * 8;
    float a = 0.f, bb = 0.f;
#pragma unroll
    for (int j = 0; j < 8; ++j) {
        a  += t1[(size_t)(e0 + j) * F_N + lane];
        bb += t2[(size_t)(e0 + j) * F_N + lane];
    }
    redA[w][lane] = a; redB[w][lane] = bb;
    __syncthreads();
    if (w == 0) {
        pt[b * 64 + lane]        = redA[0][lane] + redA[1][lane] + redA[2][lane] + redA[3][lane];
        pt[(16 + b) * 64 + lane] = redB[0][lane] + redB[1][lane] + redB[2][lane] + redB[3][lane];
    }
}

// ---------------------------------------------------------------------------
// Kernel F: tiny finalize — fold partials, matvecs, 128-float output.
// ---------------------------------------------------------------------------
__global__ __launch_bounds__(256) void k_final2(
    const float* __restrict__ pp, const float* __restrict__ pt,
    const float* __restrict__ conv_w, const float* __restrict__ conv_b,
    const float* __restrict__ gat_b, const float* __restrict__ lin_w,
    float* __restrict__ out)
{
    __shared__ float S1[64], S2[64], P0[64], P1[64], MC[64], MM[64];
    __shared__ float repD[128], repM[128];
    const int tid = threadIdx.x;
    const int w = tid >> 6, lane = tid & 63;
    if (w == 0) {
        float a = 0.f, b = 0.f;
#pragma unroll
        for (int i = 0; i < 16; ++i) { a += pp[i * 64 + lane]; b += pp[(16 + i) * 64 + lane]; }
        P0[lane] = a; MC[lane] = b * (1.f / (float)D_N);
    } else if (w == 1) {
        float a = 0.f, b = 0.f;
#pragma unroll
        for (int i = 0; i < 32; ++i) { a += pp[(32 + i) * 64 + lane]; b += pp[(64 + i) * 64 + lane]; }
        P1[lane] = a; MM[lane] = b * (1.f / (float)M_N);
    } else if (w == 2) {
        float a = 0.f, b = 0.f;
#pragma unroll
        for (int i = 0; i < 16; ++i) { a += pt[i * 64 + lane]; b += pt[(16 + i) * 64 + lane]; }
        S1[lane] = a; S2[lane] = b * (1.f / (float)D_N);
    }
    __syncthreads();
    if (tid < 64) {
        float dia = conv_b[lane], med = conv_b[lane];
#pragma unroll 8
        for (int j = 0; j < 64; ++j) {
            dia += MC[j] * conv_w[lane * 64 + j];
            med += MM[j] * conv_w[lane * 64 + j];
        }
        repD[lane]      = S1[lane] + (float)D_N * gat_b[lane];
        repD[64 + lane] = (float)D_N * dia;
        repM[lane]      = S2[lane] + (float)M_N * gat_b[lane];
        repM[64 + lane] = (float)M_N * med;
    }
    __syncthreads();
    if (tid < 64) {
        float o1 = P0[lane], o2 = P1[lane];
#pragma unroll 8
        for (int j = 0; j < 128; ++j) {
            o1 += repD[j] * lin_w[lane * 128 + j];
            o2 += repM[j] * lin_w[lane * 128 + j];
        }
        out[lane] = o1;
        out[64 + lane] = o2;
    }
}

extern "C" void kernel_launch(void* const* d_in, const int* in_sizes, int n_in,
                              void* d_out, int out_size, void* d_ws, size_t ws_size,
                              hipStream_t stream) {
    const int*   c_it    = (const int*)d_in[0];
    const int*   m_it    = (const int*)d_in[1];
    const float* c_emb   = (const float*)d_in[2];
    const float* m_emb   = (const float*)d_in[3];
    const float* pe0     = (const float*)d_in[4];
    const float* pe1     = (const float*)d_in[5];
    const float* conv_w  = (const float*)d_in[6];
    const float* conv_b  = (const float*)d_in[7];
    const float* gat_w   = (const float*)d_in[8];
    const float* gat_b   = (const float*)d_in[9];
    const float* gat_att = (const float*)d_in[10];
    const float* hattr   = (const float*)d_in[11];
    const float* lin_w   = (const float*)d_in[12];
    float* out = (float*)d_out;

    float* ws = (float*)d_ws;
    float* xw = ws;                                  // 1536*64
    float* u  = xw + (D_N + M_N) * F_N;              // 1536
    float* t1 = u + (D_N + M_N);                     // 512*64
    float* t2 = t1 + D_N * F_N;                      // 512*64
    float* pp = t2 + D_N * F_N;                      // 96*64
    float* pt = pp + 96 * 64;                        // 32*64

    k_gather<<<48, 256, 0, stream>>>(c_it, m_it, pe0, pe1, c_emb, m_emb, pp);
    k_xw<<<(D_N + M_N) / 4, 256, 0, stream>>>(c_it, m_it, c_emb, m_emb,
                                              gat_w, gat_att, xw, u);
    k_edge<<<D_N, 256, 0, stream>>>(hattr, gat_w, gat_att, xw, u, t1, t2);
    k_redt<<<16, 256, 0, stream>>>(t1, t2, pt);
    k_final2<<<1, 256, 0, stream>>>(pp, pt, conv_w, conv_b, gat_b, lin_w, out);
}